// Round 2
// baseline (2977.878 us; speedup 1.0000x reference)
//
#include <hip/hip_runtime.h>

#define BS 16
#define SEQ 1024
#define EMB 128
#define NHEAD 4
#define LN_EPS 1e-5f

typedef __attribute__((ext_vector_type(8))) short bf16x8;
typedef __attribute__((ext_vector_type(4))) float f32x4;
typedef __attribute__((ext_vector_type(4))) unsigned short u16x4;

__device__ __forceinline__ unsigned short f2b(float f) {
  union { float f; unsigned u; } v; v.f = f;
  unsigned r = v.u + 0x7fff + ((v.u >> 16) & 1);
  return (unsigned short)(r >> 16);
}
// split x into hi+lo bf16 (3-term Markidis precision: rel err ~2^-17)
__device__ __forceinline__ void split2(float x, unsigned short& hi, unsigned short& lo) {
  unsigned short h = f2b(x);
  float hf = __uint_as_float((unsigned)h << 16);
  hi = h; lo = f2b(x - hf);
}
__device__ __forceinline__ float rsqrt_acc(float v) {
  float r = rsqrtf(v);
  return r * (1.5f - 0.5f * v * r * r);   // one Newton step -> ~f32-exact
}

// ---------------- weight prep ----------------
// out[l][n][k](hi at [idx], lo at [PL+idx]) = in[l][k][n], zero-padded
__global__ void k_transpose_pad(const float* __restrict__ in, unsigned short* __restrict__ out,
                                size_t PL, int L, int Kin, int Nin, int Kout, int Nout) {
  int idx = blockIdx.x * 256 + threadIdx.x;
  int total = L * Kout * Nout;
  if (idx >= total) return;
  int k = idx % Kout;
  int n = (idx / Kout) % Nout;
  int l = idx / (Kout * Nout);
  float v = (k < Kin && n < Nin) ? in[(size_t)l * Kin * Nin + (size_t)k * Nin + n] : 0.f;
  unsigned short hi, lo; split2(v, hi, lo);
  out[idx] = hi; out[PL + idx] = lo;
}

// qvWT[l][512][128]: n<256 -> q (qW rows -> H dims 64..126), n>=256 -> v (H dims 0..62)
__global__ void k_prep_qv(const float* __restrict__ qW, const float* __restrict__ vW,
                          unsigned short* __restrict__ out, size_t PL) {
  int idx = blockIdx.x * 256 + threadIdx.x;
  int total = 11 * 512 * 128;
  if (idx >= total) return;
  int k = idx & 127;
  int n = (idx >> 7) & 511;
  int l = idx >> 16;
  float v = 0.f;
  if (n < 256) {
    if (n < 252 && k >= 64 && k < 127) v = qW[(size_t)l * 63 * 252 + (size_t)(k - 64) * 252 + n];
  } else {
    int n2 = n - 256;
    if (n2 < 252 && k < 63) v = vW[(size_t)l * 63 * 252 + (size_t)k * 252 + n2];
  }
  unsigned short hi, lo; split2(v, hi, lo);
  out[idx] = hi; out[PL + idx] = lo;
}

// ---------------- combine + read_in ----------------
__global__ void k_combine_readin(const float* __restrict__ xs, const float* __restrict__ ys,
                                 const float* __restrict__ W, const float* __restrict__ bias,
                                 float* __restrict__ H, unsigned short* __restrict__ Hbf, size_t hbPl) {
  int blk = blockIdx.x;            // b*1024 + t
  int b = blk >> 10, t = blk & 1023, p = t >> 1;
  __shared__ float zs[64];
  int tid = threadIdx.x;           // 128
  if (tid < 64) {
    float v;
    if (tid < 63) v = xs[((size_t)b * 512 + p) * 63 + tid];
    else v = (t & 1) ? ys[(size_t)b * 512 + p] : 0.f;
    zs[tid] = v;
  }
  __syncthreads();
  float acc = bias[tid];
  #pragma unroll 8
  for (int d = 0; d < 64; ++d) acc += zs[d] * W[d * 128 + tid];
  size_t o = (size_t)blk * 128 + tid;
  H[o] = acc;
  unsigned short hi, lo; split2(acc, hi, lo);
  Hbf[o] = hi; Hbf[hbPl + o] = lo;
}

// ---------------- generic split-precision MFMA GEMM ----------------
// C = act(A @ BT^T + bias), 3-term split on both operands.
// MODE 0: bf16-split out0[row*N+c]      MODE 1: f32 outF[row*N+c]
// MODE 2: last qkv (N=1536): q,k normal [b][h][t][128]; v transposed [b][h][d][t]
// MODE 3: qv63 (N=512): c<256 q normal [b][h][t][64] (d63=0); else v transposed [b][h][d][t] (d63=0)
template<int MODE, bool RELU>
__global__ __launch_bounds__(256) void k_gemm(
    const unsigned short* __restrict__ A, int aStride, size_t aPl,
    const unsigned short* __restrict__ BT, size_t bPl, const float* __restrict__ bias,
    int N, int K,
    unsigned short* __restrict__ out0, size_t o0Pl,
    unsigned short* __restrict__ out1, size_t o1Pl,
    unsigned short* __restrict__ out2, size_t o2Pl,
    float* __restrict__ outF) {
  int wid = threadIdx.x >> 6, lane = threadIdx.x & 63;
  int lr = lane & 15, lg = lane >> 4;
  int row0 = blockIdx.x * 64 + wid * 16;
  int n0 = blockIdx.y * 64;
  f32x4 acc[4] = {};
  const unsigned short* aP = A + (size_t)(row0 + lr) * aStride + lg * 8;
  const unsigned short* bP = BT + (size_t)n0 * K + lg * 8;
  for (int k0 = 0; k0 < K; k0 += 32) {
    bf16x8 ah = *reinterpret_cast<const bf16x8*>(aP + k0);
    bf16x8 al = *reinterpret_cast<const bf16x8*>(aP + aPl + k0);
    #pragma unroll
    for (int nf = 0; nf < 4; ++nf) {
      const unsigned short* bpp = bP + (size_t)(nf * 16 + lr) * K + k0;
      bf16x8 bh = *reinterpret_cast<const bf16x8*>(bpp);
      bf16x8 bl = *reinterpret_cast<const bf16x8*>(bpp + bPl);
      acc[nf] = __builtin_amdgcn_mfma_f32_16x16x32_bf16(ah, bh, acc[nf], 0, 0, 0);
      acc[nf] = __builtin_amdgcn_mfma_f32_16x16x32_bf16(al, bh, acc[nf], 0, 0, 0);
      acc[nf] = __builtin_amdgcn_mfma_f32_16x16x32_bf16(ah, bl, acc[nf], 0, 0, 0);
    }
  }
  int rowb = row0 + lg * 4;
  #pragma unroll
  for (int nf = 0; nf < 4; ++nf) {
    int c = n0 + nf * 16 + lr;
    float bv = bias ? bias[c] : 0.f;
    float vr[4];
    #pragma unroll
    for (int r = 0; r < 4; ++r) {
      float v = acc[nf][r] + bv;
      vr[r] = RELU ? fmaxf(v, 0.f) : v;
    }
    if (MODE == 0) {
      #pragma unroll
      for (int r = 0; r < 4; ++r) {
        unsigned short hi, lo; split2(vr[r], hi, lo);
        size_t o = (size_t)(rowb + r) * N + c;
        out0[o] = hi; out0[o0Pl + o] = lo;
      }
    } else if (MODE == 1) {
      #pragma unroll
      for (int r = 0; r < 4; ++r) outF[(size_t)(rowb + r) * N + c] = vr[r];
    } else if (MODE == 2) {
      int tsel = c >> 9, c2 = c & 511, hh = c2 >> 7, d = c2 & 127;
      int b = rowb >> 10, t = rowb & 1023;
      size_t bh = (size_t)b * NHEAD + hh;
      if (tsel < 2) {
        unsigned short* base = tsel ? out1 : out0;
        size_t pl = tsel ? o1Pl : o0Pl;
        #pragma unroll
        for (int r = 0; r < 4; ++r) {
          unsigned short hi, lo; split2(vr[r], hi, lo);
          size_t o = (bh * SEQ + (size_t)(t + r)) * 128 + d;
          base[o] = hi; base[pl + o] = lo;
        }
      } else {
        u16x4 hv, lv;
        #pragma unroll
        for (int r = 0; r < 4; ++r) { unsigned short hi, lo; split2(vr[r], hi, lo); hv[r] = hi; lv[r] = lo; }
        size_t addr = (bh * 128 + d) * SEQ + t;
        *reinterpret_cast<u16x4*>(out2 + addr) = hv;
        *reinterpret_cast<u16x4*>(out2 + o2Pl + addr) = lv;
      }
    } else {  // MODE 3
      int b = rowb >> 10, t = rowb & 1023;
      if (c < 256) {
        int hh, d; bool pad = (c >= 252);
        if (!pad) { hh = c / 63; d = c - hh * 63; } else { hh = c - 252; d = 63; }
        size_t bh = (size_t)b * NHEAD + hh;
        #pragma unroll
        for (int r = 0; r < 4; ++r) {
          float v = pad ? 0.f : vr[r];
          unsigned short hi, lo; split2(v, hi, lo);
          size_t o = (bh * SEQ + (size_t)(t + r)) * 64 + d;
          out0[o] = hi; out0[o0Pl + o] = lo;
        }
      } else {
        int cc = c - 256; int hh, d; bool pad = (cc >= 252);
        if (!pad) { hh = cc / 63; d = cc - hh * 63; } else { hh = cc - 252; d = 63; }
        size_t bh = (size_t)b * NHEAD + hh;
        u16x4 hv, lv;
        #pragma unroll
        for (int r = 0; r < 4; ++r) {
          float v = pad ? 0.f : vr[r];
          unsigned short hi, lo; split2(v, hi, lo); hv[r] = hi; lv[r] = lo;
        }
        size_t addr = (bh * 64 + d) * SEQ + t;
        *reinterpret_cast<u16x4*>(out1 + addr) = hv;
        *reinterpret_cast<u16x4*>(out1 + o1Pl + addr) = lv;
      }
    }
  }
}

// ---------------- fused attention (+LN1), split precision ----------------
template<int DHEAD>
__global__ __launch_bounds__(256) void k_attn(
    const unsigned short* __restrict__ q, size_t qPl,
    const unsigned short* __restrict__ kbase, size_t kPl, size_t kBStride, size_t kHStride,
    const unsigned short* __restrict__ vT, size_t vPl,
    const float* __restrict__ head_mask,
    float* __restrict__ Hst, unsigned short* __restrict__ HbfOut, size_t hbPl,
    const float* __restrict__ g, const float* __restrict__ bta) {
  constexpr int KF = DHEAD / 32, NFO = DHEAD / 16;
  constexpr int NT = SEQ / 32;
  constexpr int SSB = 4 * 2 * 32 * 40 * 2;
  constexpr int SH_BYTES = (SSB > 32 * DHEAD * 4) ? SSB : 32 * DHEAD * 4;
  int b = blockIdx.x >> 4, pidx = blockIdx.x & 15;
  int wid = threadIdx.x >> 6, lane = threadIdx.x & 63;
  int lr = lane & 15, lg = lane >> 4;
  int h = wid;
  __shared__ __align__(16) char shraw[SH_BYTES];
  typedef unsigned short SArr[2][32][40];
  SArr* sS = (SArr*)shraw;             // sS[w][plane][r][c]
  typedef float FRow[DHEAD];
  FRow* facc = (FRow*)shraw;           // facc[r][c] (aliases sS)
  const unsigned short* qh = q + (size_t)(b * NHEAD + h) * SEQ * DHEAD;
  const unsigned short* kh = kbase + (size_t)b * kBStride + (size_t)h * kHStride;
  const unsigned short* vh = vT + (size_t)(b * NHEAD + h) * DHEAD * SEQ;
  float hm = head_mask[h];
  float hm3 = hm * hm * hm;

  for (int s = 0; s < 2; ++s) {
    int tile = (s == 0) ? pidx : (NT - 1 - pidx);
    int i0 = tile * 32;
    bf16x8 qfh[2][KF], qfl[2][KF];
    #pragma unroll
    for (int mf = 0; mf < 2; ++mf)
      #pragma unroll
      for (int kf = 0; kf < KF; ++kf) {
        const unsigned short* qp = qh + (size_t)(i0 + mf * 16 + lr) * DHEAD + kf * 32 + lg * 8;
        qfh[mf][kf] = *reinterpret_cast<const bf16x8*>(qp);
        qfl[mf][kf] = *reinterpret_cast<const bf16x8*>(qp + qPl);
      }
    f32x4 oacc[2][NFO] = {};
    int jend = i0 + 32;
    for (int j0 = 0; j0 < jend; j0 += 32) {
      #pragma unroll
      for (int nf2 = 0; nf2 < 2; ++nf2) {
        int j16 = j0 + nf2 * 16;
        bf16x8 kfh[KF], kfl[KF];
        #pragma unroll
        for (int kf = 0; kf < KF; ++kf) {
          const unsigned short* kp = kh + (size_t)(j16 + lr) * EMB + kf * 32 + lg * 8;
          kfh[kf] = *reinterpret_cast<const bf16x8*>(kp);
          kfl[kf] = *reinterpret_cast<const bf16x8*>(kp + kPl);
        }
        #pragma unroll
        for (int mf = 0; mf < 2; ++mf) {
          f32x4 sacc = {};
          #pragma unroll
          for (int kf = 0; kf < KF; ++kf) {
            sacc = __builtin_amdgcn_mfma_f32_16x16x32_bf16(qfh[mf][kf], kfh[kf], sacc, 0, 0, 0);
            sacc = __builtin_amdgcn_mfma_f32_16x16x32_bf16(qfl[mf][kf], kfh[kf], sacc, 0, 0, 0);
            sacc = __builtin_amdgcn_mfma_f32_16x16x32_bf16(qfh[mf][kf], kfl[kf], sacc, 0, 0, 0);
          }
          #pragma unroll
          for (int r = 0; r < 4; ++r) {
            int i = i0 + mf * 16 + lg * 4 + r;
            int j = j16 + lr;
            float v = (j <= i) ? fmaxf(sacc[r], 0.f) : 0.f;
            unsigned short shi, slo; split2(v, shi, slo);
            sS[wid][0][mf * 16 + lg * 4 + r][nf2 * 16 + lr] = shi;
            sS[wid][1][mf * 16 + lg * 4 + r][nf2 * 16 + lr] = slo;
          }
        }
      }
      asm volatile("s_waitcnt lgkmcnt(0)" ::: "memory");
      __builtin_amdgcn_sched_barrier(0);
      #pragma unroll
      for (int mf = 0; mf < 2; ++mf) {
        bf16x8 sfh = *reinterpret_cast<const bf16x8*>(&sS[wid][0][mf * 16 + lr][lg * 8]);
        bf16x8 sfl = *reinterpret_cast<const bf16x8*>(&sS[wid][1][mf * 16 + lr][lg * 8]);
        #pragma unroll
        for (int nf = 0; nf < NFO; ++nf) {
          const unsigned short* vp = vh + (size_t)(nf * 16 + lr) * SEQ + j0 + lg * 8;
          bf16x8 vfh = *reinterpret_cast<const bf16x8*>(vp);
          bf16x8 vfl = *reinterpret_cast<const bf16x8*>(vp + vPl);
          oacc[mf][nf] = __builtin_amdgcn_mfma_f32_16x16x32_bf16(sfh, vfh, oacc[mf][nf], 0, 0, 0);
          oacc[mf][nf] = __builtin_amdgcn_mfma_f32_16x16x32_bf16(sfl, vfh, oacc[mf][nf], 0, 0, 0);
          oacc[mf][nf] = __builtin_amdgcn_mfma_f32_16x16x32_bf16(sfh, vfl, oacc[mf][nf], 0, 0, 0);
        }
      }
    }
    __syncthreads();  // all waves done with sS (facc aliases it)
    for (int x = threadIdx.x; x < 32 * DHEAD; x += 256) ((float*)shraw)[x] = 0.f;
    __syncthreads();
    for (int w = 0; w < 4; ++w) {   // deterministic head-sum
      if (wid == w) {
        #pragma unroll
        for (int mf = 0; mf < 2; ++mf)
          #pragma unroll
          for (int nf = 0; nf < NFO; ++nf)
            #pragma unroll
            for (int r = 0; r < 4; ++r) {
              int rr = mf * 16 + lg * 4 + r;
              facc[rr][nf * 16 + lr] += oacc[mf][nf][r] * hm3 / (float)(i0 + rr + 1);
            }
      }
      __syncthreads();
    }
    // fused residual + LN1 (H in-place; bf16-split out to HbfOut)
    for (int rl = 0; rl < 8; ++rl) {
      int rr = wid * 8 + rl;
      size_t row = ((size_t)b * SEQ + i0 + rr) * EMB;
      int c0 = lane, c1 = lane + 64;
      float a0 = (DHEAD == 128) ? facc[rr][c0] : 0.f;
      float a1 = (DHEAD == 128) ? facc[rr][c1] : facc[rr][lane];
      float x0 = Hst[row + c0] + a0;
      float x1 = Hst[row + c1] + a1;
      float s1 = x0 + x1, s2 = x0 * x0 + x1 * x1;
      #pragma unroll
      for (int off = 1; off < 64; off <<= 1) {
        s1 += __shfl_xor(s1, off);
        s2 += __shfl_xor(s2, off);
      }
      float mu = s1 * (1.f / 128.f);
      float var = s2 * (1.f / 128.f) - mu * mu;
      float rs = rsqrt_acc(var + LN_EPS);
      float y0 = (x0 - mu) * rs * g[c0] + bta[c0];
      float y1 = (x1 - mu) * rs * g[c1] + bta[c1];
      Hst[row + c0] = y0; Hst[row + c1] = y1;
      unsigned short h0, l0, h1, l1; split2(y0, h0, l0); split2(y1, h1, l1);
      HbfOut[row + c0] = h0; HbfOut[hbPl + row + c0] = l0;
      HbfOut[row + c1] = h1; HbfOut[hbPl + row + c1] = l1;
    }
    __syncthreads();
  }
}

// ---------------- residual + LN2 ----------------
__global__ __launch_bounds__(256) void k_ln(const float* __restrict__ X,
                                            float* __restrict__ Hst,
                                            unsigned short* __restrict__ HbfOut, size_t hbPl,
                                            const float* __restrict__ g, const float* __restrict__ bta) {
  int wid = threadIdx.x >> 6, lane = threadIdx.x & 63;
  size_t row = ((size_t)blockIdx.x * 4 + wid) * EMB;
  int c0 = lane, c1 = lane + 64;
  float x0 = Hst[row + c0] + X[row + c0];
  float x1 = Hst[row + c1] + X[row + c1];
  float s1 = x0 + x1, s2 = x0 * x0 + x1 * x1;
  #pragma unroll
  for (int off = 1; off < 64; off <<= 1) {
    s1 += __shfl_xor(s1, off);
    s2 += __shfl_xor(s2, off);
  }
  float mu = s1 * (1.f / 128.f);
  float var = s2 * (1.f / 128.f) - mu * mu;
  float rs = rsqrt_acc(var + LN_EPS);
  float y0 = (x0 - mu) * rs * g[c0] + bta[c0];
  float y1 = (x1 - mu) * rs * g[c1] + bta[c1];
  Hst[row + c0] = y0; Hst[row + c1] = y1;
  unsigned short h0, l0, h1, l1; split2(y0, h0, l0); split2(y1, h1, l1);
  HbfOut[row + c0] = h0; HbfOut[hbPl + row + c0] = l0;
  HbfOut[row + c1] = h1; HbfOut[hbPl + row + c1] = l1;
}

// ---------------- readout ----------------
__global__ __launch_bounds__(64) void k_readout(const float* __restrict__ H,
                                                const float* __restrict__ W, const float* __restrict__ b0,
                                                float* __restrict__ out) {
  int idx = blockIdx.x;           // b*512 + p
  int b = idx >> 9, p = idx & 511;
  size_t row = ((size_t)b * SEQ + 2 * p) * EMB;
  int lane = threadIdx.x;
  float acc = H[row + lane] * W[lane] + H[row + 64 + lane] * W[64 + lane];
  #pragma unroll
  for (int off = 1; off < 64; off <<= 1) acc += __shfl_xor(acc, off);
  if (lane == 0) out[idx] = acc + b0[0];
}

extern "C" void kernel_launch(void* const* d_in, const int* in_sizes, int n_in,
                              void* d_out, int out_size, void* d_ws, size_t ws_size,
                              hipStream_t stream) {
  (void)in_sizes; (void)n_in; (void)out_size; (void)ws_size;
  const float* xs        = (const float*)d_in[0];
  const float* ys        = (const float*)d_in[1];
  const float* head_mask = (const float*)d_in[2];
  const float* read_in_W = (const float*)d_in[3];
  const float* read_in_b = (const float*)d_in[4];
  const float* qW        = (const float*)d_in[5];
  const float* vW        = (const float*)d_in[6];
  const float* qW_last   = (const float*)d_in[7];
  const float* kW_last   = (const float*)d_in[8];
  const float* vW_last   = (const float*)d_in[9];
  const float* ln1_g     = (const float*)d_in[10];
  const float* ln1_b     = (const float*)d_in[11];
  const float* ln2_g     = (const float*)d_in[12];
  const float* ln2_b     = (const float*)d_in[13];
  const float* mlp_W1    = (const float*)d_in[14];
  const float* mlp_b1    = (const float*)d_in[15];
  const float* mlp_W2    = (const float*)d_in[16];
  const float* mlp_b2    = (const float*)d_in[17];
  const float* ro_W      = (const float*)d_in[18];
  const float* ro_b      = (const float*)d_in[19];

  const size_t HPL   = (size_t)BS * SEQ * EMB;          // 2M
  const size_t QPL   = (size_t)BS * NHEAD * SEQ * 128;  // 8M
  const size_t VT64PL= (size_t)BS * NHEAD * 64 * SEQ;   // 4M
  const size_t MIDPL = (size_t)BS * SEQ * 512;          // 8M
  const size_t KMPL  = QPL;                              // 8M
  const size_t VTLPL = QPL;                              // 8M
  const size_t QVWPL = (size_t)11 * 512 * 128;
  const size_t W1PL  = (size_t)12 * 128 * 512;
  const size_t W2PL  = (size_t)12 * 512 * 128;
  const size_t LASTPL= (size_t)3 * 512 * 128;

  char* ws = (char*)d_ws;
  size_t off = 0;
  auto alloc = [&](size_t bytes) -> void* {
    void* p = ws + off;
    off += (bytes + 255) & ~(size_t)255;
    return p;
  };
  float* H             = (float*)alloc(HPL * 4);                  // 8 MB (in-place state)
  unsigned short* Hbf  = (unsigned short*)alloc(2 * HPL * 2);     // 8 MB
  unsigned short* Hbf2 = (unsigned short*)alloc(2 * HPL * 2);     // 8 MB
  unsigned short* qbuf = (unsigned short*)alloc(2 * QPL * 2);     // 32 MB
  float* resid = (float*)qbuf;   // alias: resid lives mlp2->ln2; qbuf lives proj->attn
  unsigned short* kmid = (unsigned short*)alloc(2 * KMPL * 2);    // 32 MB (vT(0-10) / mid / K-last)
  unsigned short* vTl  = (unsigned short*)alloc(2 * VTLPL * 2);   // 32 MB (last-layer vT)
  unsigned short* qvWT = (unsigned short*)alloc(2 * QVWPL * 2);
  unsigned short* W1T  = (unsigned short*)alloc(2 * W1PL * 2);
  unsigned short* W2T  = (unsigned short*)alloc(2 * W2PL * 2);
  unsigned short* lastT= (unsigned short*)alloc(2 * LASTPL * 2);

  { int tot = 11 * 512 * 128; k_prep_qv<<<dim3((tot + 255) / 256), 256, 0, stream>>>(qW, vW, qvWT, QVWPL); }
  { int tot = 12 * 512 * 128; k_transpose_pad<<<dim3((tot + 255) / 256), 256, 0, stream>>>(mlp_W1, W1T, W1PL, 12, 128, 512, 128, 512); }
  { int tot = 12 * 128 * 512; k_transpose_pad<<<dim3((tot + 255) / 256), 256, 0, stream>>>(mlp_W2, W2T, W2PL, 12, 512, 128, 512, 128); }
  { int tot = 512 * 128;
    k_transpose_pad<<<dim3((tot + 255) / 256), 256, 0, stream>>>(qW_last, lastT,          LASTPL, 1, 128, 512, 128, 512);
    k_transpose_pad<<<dim3((tot + 255) / 256), 256, 0, stream>>>(kW_last, lastT + 65536,  LASTPL, 1, 128, 512, 128, 512);
    k_transpose_pad<<<dim3((tot + 255) / 256), 256, 0, stream>>>(vW_last, lastT + 131072, LASTPL, 1, 128, 512, 128, 512); }

  k_combine_readin<<<dim3(BS * SEQ), 128, 0, stream>>>(xs, ys, read_in_W, read_in_b, H, Hbf, HPL);

  for (int l = 0; l < 11; ++l) {
    // fused q+v projection; v written directly transposed into kmid
    k_gemm<3, false><<<dim3(256, 8), 256, 0, stream>>>(
        Hbf, 128, HPL, qvWT + (size_t)l * 65536, QVWPL, nullptr, 512, 128,
        qbuf, QPL, kmid, VT64PL, nullptr, 0, nullptr);
    k_attn<64><<<dim3(256), 256, 0, stream>>>(
        qbuf, QPL, Hbf, HPL, (size_t)SEQ * EMB, 0, kmid, VT64PL, head_mask,
        H, Hbf2, HPL, ln1_g + l * 128, ln1_b + l * 128);
    k_gemm<0, true><<<dim3(256, 8), 256, 0, stream>>>(
        Hbf2, 128, HPL, W1T + (size_t)l * 65536, W1PL, mlp_b1 + l * 512, 512, 128,
        kmid, MIDPL, nullptr, 0, nullptr, 0, nullptr);
    k_gemm<1, false><<<dim3(256, 2), 256, 0, stream>>>(
        kmid, 512, MIDPL, W2T + (size_t)l * 65536, W2PL, mlp_b2 + l * 128, 128, 512,
        nullptr, 0, nullptr, 0, nullptr, 0, resid);
    k_ln<<<dim3(4096), 256, 0, stream>>>(resid, H, Hbf, HPL, ln2_g + l * 128, ln2_b + l * 128);
  }
  // last layer
  k_gemm<2, false><<<dim3(256, 24), 256, 0, stream>>>(
      Hbf, 128, HPL, lastT, LASTPL, nullptr, 1536, 128,
      qbuf, QPL, kmid, KMPL, vTl, VTLPL, nullptr);
  k_attn<128><<<dim3(256), 256, 0, stream>>>(
      qbuf, QPL, kmid, KMPL, (size_t)NHEAD * SEQ * 128, (size_t)SEQ * 128, vTl, VTLPL, head_mask,
      H, Hbf2, HPL, ln1_g + 11 * 128, ln1_b + 11 * 128);
  k_gemm<0, true><<<dim3(256, 8), 256, 0, stream>>>(
      Hbf2, 128, HPL, W1T + (size_t)11 * 65536, W1PL, mlp_b1 + 11 * 512, 512, 128,
      kmid, MIDPL, nullptr, 0, nullptr, 0, nullptr);
  k_gemm<1, false><<<dim3(256, 2), 256, 0, stream>>>(
      kmid, 512, MIDPL, W2T + (size_t)11 * 65536, W2PL, mlp_b2 + 11 * 128, 128, 512,
      nullptr, 0, nullptr, 0, nullptr, 0, resid);
  k_ln<<<dim3(4096), 256, 0, stream>>>(resid, H, Hbf, HPL, ln2_g + 11 * 128, ln2_b + 11 * 128);

  k_readout<<<dim3(8192), 64, 0, stream>>>(H, ro_W, ro_b, (float*)d_out);
}

// Round 3
// 2684.231 us; speedup vs baseline: 1.1094x; 1.1094x over previous
//
#include <hip/hip_runtime.h>

#define BS 16
#define SEQ 1024
#define EMB 128
#define NHEAD 4
#define LN_EPS 1e-5f

typedef __attribute__((ext_vector_type(8))) short bf16x8;
typedef __attribute__((ext_vector_type(4))) float f32x4;
typedef __attribute__((ext_vector_type(4))) unsigned short u16x4;

__device__ __forceinline__ unsigned short f2b(float f) {
  union { float f; unsigned u; } v; v.f = f;
  unsigned r = v.u + 0x7fff + ((v.u >> 16) & 1);
  return (unsigned short)(r >> 16);
}
// split x into hi+lo bf16 (3-term Markidis precision: rel err ~2^-17)
__device__ __forceinline__ void split2(float x, unsigned short& hi, unsigned short& lo) {
  unsigned short h = f2b(x);
  float hf = __uint_as_float((unsigned)h << 16);
  hi = h; lo = f2b(x - hf);
}
__device__ __forceinline__ float rsqrt_acc(float v) {
  float r = rsqrtf(v);
  return r * (1.5f - 0.5f * v * r * r);   // one Newton step -> ~f32-exact
}

// ---------------- weight prep ----------------
// out[l][n][k](hi at [idx], lo at [PL+idx]) = in[l][k][n], zero-padded
__global__ void k_transpose_pad(const float* __restrict__ in, unsigned short* __restrict__ out,
                                size_t PL, int L, int Kin, int Nin, int Kout, int Nout) {
  int idx = blockIdx.x * 256 + threadIdx.x;
  int total = L * Kout * Nout;
  if (idx >= total) return;
  int k = idx % Kout;
  int n = (idx / Kout) % Nout;
  int l = idx / (Kout * Nout);
  float v = (k < Kin && n < Nin) ? in[(size_t)l * Kin * Nin + (size_t)k * Nin + n] : 0.f;
  unsigned short hi, lo; split2(v, hi, lo);
  out[idx] = hi; out[PL + idx] = lo;
}

// qvWT[l][512][128]: n<256 -> q (qW rows -> H dims 64..126), n>=256 -> v (H dims 0..62)
__global__ void k_prep_qv(const float* __restrict__ qW, const float* __restrict__ vW,
                          unsigned short* __restrict__ out, size_t PL) {
  int idx = blockIdx.x * 256 + threadIdx.x;
  int total = 11 * 512 * 128;
  if (idx >= total) return;
  int k = idx & 127;
  int n = (idx >> 7) & 511;
  int l = idx >> 16;
  float v = 0.f;
  if (n < 256) {
    if (n < 252 && k >= 64 && k < 127) v = qW[(size_t)l * 63 * 252 + (size_t)(k - 64) * 252 + n];
  } else {
    int n2 = n - 256;
    if (n2 < 252 && k < 63) v = vW[(size_t)l * 63 * 252 + (size_t)k * 252 + n2];
  }
  unsigned short hi, lo; split2(v, hi, lo);
  out[idx] = hi; out[PL + idx] = lo;
}

// ---------------- combine + read_in ----------------
__global__ void k_combine_readin(const float* __restrict__ xs, const float* __restrict__ ys,
                                 const float* __restrict__ W, const float* __restrict__ bias,
                                 float* __restrict__ H, unsigned short* __restrict__ Hbf, size_t hbPl) {
  int blk = blockIdx.x;            // b*1024 + t
  int b = blk >> 10, t = blk & 1023, p = t >> 1;
  __shared__ float zs[64];
  int tid = threadIdx.x;           // 128
  if (tid < 64) {
    float v;
    if (tid < 63) v = xs[((size_t)b * 512 + p) * 63 + tid];
    else v = (t & 1) ? ys[(size_t)b * 512 + p] : 0.f;
    zs[tid] = v;
  }
  __syncthreads();
  float acc = bias[tid];
  #pragma unroll 8
  for (int d = 0; d < 64; ++d) acc += zs[d] * W[d * 128 + tid];
  size_t o = (size_t)blk * 128 + tid;
  H[o] = acc;
  unsigned short hi, lo; split2(acc, hi, lo);
  Hbf[o] = hi; Hbf[hbPl + o] = lo;
}

// ---------------- generic split-precision MFMA GEMM ----------------
// C = act(A @ BT^T + bias), 3-term split on both operands.
// MODE 0: bf16-split out0[row*N+c]      MODE 1: f32 outF[row*N+c]
// MODE 2: last qkv (N=1536): q,k normal [b][h][t][128]; v transposed [b][h][d][t]
// MODE 3: qv63 (N=512): c<256 q normal [b][h][t][64] (d63=0); else v transposed [b][h][d][t] (d63=0)
template<int MODE, bool RELU>
__global__ __launch_bounds__(256) void k_gemm(
    const unsigned short* __restrict__ A, int aStride, size_t aPl,
    const unsigned short* __restrict__ BT, size_t bPl, const float* __restrict__ bias,
    int N, int K,
    unsigned short* __restrict__ out0, size_t o0Pl,
    unsigned short* __restrict__ out1, size_t o1Pl,
    unsigned short* __restrict__ out2, size_t o2Pl,
    float* __restrict__ outF) {
  int wid = threadIdx.x >> 6, lane = threadIdx.x & 63;
  int lr = lane & 15, lg = lane >> 4;
  int row0 = blockIdx.x * 64 + wid * 16;
  int n0 = blockIdx.y * 64;
  f32x4 acc[4] = {};
  const unsigned short* aP = A + (size_t)(row0 + lr) * aStride + lg * 8;
  const unsigned short* bP = BT + (size_t)n0 * K + lg * 8;
  for (int k0 = 0; k0 < K; k0 += 32) {
    bf16x8 ah = *reinterpret_cast<const bf16x8*>(aP + k0);
    bf16x8 al = *reinterpret_cast<const bf16x8*>(aP + aPl + k0);
    #pragma unroll
    for (int nf = 0; nf < 4; ++nf) {
      const unsigned short* bpp = bP + (size_t)(nf * 16 + lr) * K + k0;
      bf16x8 bh = *reinterpret_cast<const bf16x8*>(bpp);
      bf16x8 bl = *reinterpret_cast<const bf16x8*>(bpp + bPl);
      acc[nf] = __builtin_amdgcn_mfma_f32_16x16x32_bf16(ah, bh, acc[nf], 0, 0, 0);
      acc[nf] = __builtin_amdgcn_mfma_f32_16x16x32_bf16(al, bh, acc[nf], 0, 0, 0);
      acc[nf] = __builtin_amdgcn_mfma_f32_16x16x32_bf16(ah, bl, acc[nf], 0, 0, 0);
    }
  }
  int rowb = row0 + lg * 4;
  #pragma unroll
  for (int nf = 0; nf < 4; ++nf) {
    int c = n0 + nf * 16 + lr;
    float bv = bias ? bias[c] : 0.f;
    float vr[4];
    #pragma unroll
    for (int r = 0; r < 4; ++r) {
      float v = acc[nf][r] + bv;
      vr[r] = RELU ? fmaxf(v, 0.f) : v;
    }
    if (MODE == 0) {
      #pragma unroll
      for (int r = 0; r < 4; ++r) {
        unsigned short hi, lo; split2(vr[r], hi, lo);
        size_t o = (size_t)(rowb + r) * N + c;
        out0[o] = hi; out0[o0Pl + o] = lo;
      }
    } else if (MODE == 1) {
      #pragma unroll
      for (int r = 0; r < 4; ++r) outF[(size_t)(rowb + r) * N + c] = vr[r];
    } else if (MODE == 2) {
      int tsel = c >> 9, c2 = c & 511, hh = c2 >> 7, d = c2 & 127;
      int b = rowb >> 10, t = rowb & 1023;
      size_t bh = (size_t)b * NHEAD + hh;
      if (tsel < 2) {
        unsigned short* base = tsel ? out1 : out0;
        size_t pl = tsel ? o1Pl : o0Pl;
        #pragma unroll
        for (int r = 0; r < 4; ++r) {
          unsigned short hi, lo; split2(vr[r], hi, lo);
          size_t o = (bh * SEQ + (size_t)(t + r)) * 128 + d;
          base[o] = hi; base[pl + o] = lo;
        }
      } else {
        u16x4 hv, lv;
        #pragma unroll
        for (int r = 0; r < 4; ++r) { unsigned short hi, lo; split2(vr[r], hi, lo); hv[r] = hi; lv[r] = lo; }
        size_t addr = (bh * 128 + d) * SEQ + t;
        *reinterpret_cast<u16x4*>(out2 + addr) = hv;
        *reinterpret_cast<u16x4*>(out2 + o2Pl + addr) = lv;
      }
    } else {  // MODE 3
      int b = rowb >> 10, t = rowb & 1023;
      if (c < 256) {
        int hh, d; bool pad = (c >= 252);
        if (!pad) { hh = c / 63; d = c - hh * 63; } else { hh = c - 252; d = 63; }
        size_t bh = (size_t)b * NHEAD + hh;
        #pragma unroll
        for (int r = 0; r < 4; ++r) {
          float v = pad ? 0.f : vr[r];
          unsigned short hi, lo; split2(v, hi, lo);
          size_t o = (bh * SEQ + (size_t)(t + r)) * 64 + d;
          out0[o] = hi; out0[o0Pl + o] = lo;
        }
      } else {
        int cc = c - 256; int hh, d; bool pad = (cc >= 252);
        if (!pad) { hh = cc / 63; d = cc - hh * 63; } else { hh = cc - 252; d = 63; }
        size_t bh = (size_t)b * NHEAD + hh;
        u16x4 hv, lv;
        #pragma unroll
        for (int r = 0; r < 4; ++r) {
          float v = pad ? 0.f : vr[r];
          unsigned short hi, lo; split2(v, hi, lo); hv[r] = hi; lv[r] = lo;
        }
        size_t addr = (bh * 64 + d) * SEQ + t;
        *reinterpret_cast<u16x4*>(out1 + addr) = hv;
        *reinterpret_cast<u16x4*>(out1 + o1Pl + addr) = lv;
      }
    }
  }
}

// ---------------- fused attention (+LN1), split precision, 8-wave ----------------
// Block = (b, pair); tiles pidx & 31-pidx processed sequentially (s), j-steps split
// even/odd between wave-groups. XCD swizzle: all blocks of batch b land on XCD b/2.
template<int DHEAD>
__global__ __launch_bounds__(512) void k_attn(
    const unsigned short* __restrict__ q, size_t qPl,
    const unsigned short* __restrict__ kbase, size_t kPl, size_t kBStride, size_t kHStride,
    const unsigned short* __restrict__ vT, size_t vPl,
    const float* __restrict__ head_mask,
    float* __restrict__ Hst, unsigned short* __restrict__ HbfOut, size_t hbPl,
    const float* __restrict__ g, const float* __restrict__ bta) {
  constexpr int KF = DHEAD / 32, NFO = DHEAD / 16;
  constexpr int NT = SEQ / 32;
  constexpr int SSB = 8 * 2 * 32 * 40 * 2;   // 40 KB
  constexpr int SH_BYTES = (SSB > 32 * DHEAD * 4) ? SSB : 32 * DHEAD * 4;
  // XCD-aware swizzle: bid%8 == XCD (round-robin dispatch); batch b -> XCD b/2
  int bid = blockIdx.x;
  int xcd = bid & 7, u = bid >> 3;
  int b = xcd * 2 + (u >> 4);
  int pidx = u & 15;
  int wid = threadIdx.x >> 6, lane = threadIdx.x & 63;
  int h = wid & 3, grp = wid >> 2;        // 4 heads x 2 j-parity groups
  int lr = lane & 15, lg = lane >> 4;
  __shared__ __align__(16) char shraw[SH_BYTES];
  typedef unsigned short SArr[2][32][40];
  SArr* sS = (SArr*)shraw;             // sS[w][plane][r][c]
  typedef float FRow[DHEAD];
  FRow* facc = (FRow*)shraw;           // facc[r][c] (aliases sS)
  const unsigned short* qh = q + (size_t)(b * NHEAD + h) * SEQ * DHEAD;
  const unsigned short* kh = kbase + (size_t)b * kBStride + (size_t)h * kHStride;
  const unsigned short* vh = vT + (size_t)(b * NHEAD + h) * DHEAD * SEQ;
  float hm = head_mask[h];
  float hm3 = hm * hm * hm;

  for (int s = 0; s < 2; ++s) {
    int tile = (s == 0) ? pidx : (NT - 1 - pidx);
    int i0 = tile * 32;
    bf16x8 qfh[2][KF], qfl[2][KF];
    #pragma unroll
    for (int mf = 0; mf < 2; ++mf)
      #pragma unroll
      for (int kf = 0; kf < KF; ++kf) {
        const unsigned short* qp = qh + (size_t)(i0 + mf * 16 + lr) * DHEAD + kf * 32 + lg * 8;
        qfh[mf][kf] = *reinterpret_cast<const bf16x8*>(qp);
        qfl[mf][kf] = *reinterpret_cast<const bf16x8*>(qp + qPl);
      }
    f32x4 oacc[2][NFO] = {};
    int jend = i0 + 32;
    for (int j0 = grp * 32; j0 < jend; j0 += 64) {
      #pragma unroll
      for (int nf2 = 0; nf2 < 2; ++nf2) {
        int j16 = j0 + nf2 * 16;
        bf16x8 kfh[KF], kfl[KF];
        #pragma unroll
        for (int kf = 0; kf < KF; ++kf) {
          const unsigned short* kp = kh + (size_t)(j16 + lr) * EMB + kf * 32 + lg * 8;
          kfh[kf] = *reinterpret_cast<const bf16x8*>(kp);
          kfl[kf] = *reinterpret_cast<const bf16x8*>(kp + kPl);
        }
        #pragma unroll
        for (int mf = 0; mf < 2; ++mf) {
          f32x4 sacc = {};
          #pragma unroll
          for (int kf = 0; kf < KF; ++kf) {
            sacc = __builtin_amdgcn_mfma_f32_16x16x32_bf16(qfh[mf][kf], kfh[kf], sacc, 0, 0, 0);
            sacc = __builtin_amdgcn_mfma_f32_16x16x32_bf16(qfl[mf][kf], kfh[kf], sacc, 0, 0, 0);
            sacc = __builtin_amdgcn_mfma_f32_16x16x32_bf16(qfh[mf][kf], kfl[kf], sacc, 0, 0, 0);
          }
          #pragma unroll
          for (int r = 0; r < 4; ++r) {
            int i = i0 + mf * 16 + lg * 4 + r;
            int j = j16 + lr;
            float v = (j <= i) ? fmaxf(sacc[r], 0.f) : 0.f;
            unsigned short shi, slo; split2(v, shi, slo);
            sS[wid][0][mf * 16 + lg * 4 + r][nf2 * 16 + lr] = shi;
            sS[wid][1][mf * 16 + lg * 4 + r][nf2 * 16 + lr] = slo;
          }
        }
      }
      asm volatile("s_waitcnt lgkmcnt(0)" ::: "memory");
      __builtin_amdgcn_sched_barrier(0);
      #pragma unroll
      for (int mf = 0; mf < 2; ++mf) {
        bf16x8 sfh = *reinterpret_cast<const bf16x8*>(&sS[wid][0][mf * 16 + lr][lg * 8]);
        bf16x8 sfl = *reinterpret_cast<const bf16x8*>(&sS[wid][1][mf * 16 + lr][lg * 8]);
        #pragma unroll
        for (int nf = 0; nf < NFO; ++nf) {
          const unsigned short* vp = vh + (size_t)(nf * 16 + lr) * SEQ + j0 + lg * 8;
          bf16x8 vfh = *reinterpret_cast<const bf16x8*>(vp);
          bf16x8 vfl = *reinterpret_cast<const bf16x8*>(vp + vPl);
          oacc[mf][nf] = __builtin_amdgcn_mfma_f32_16x16x32_bf16(sfh, vfh, oacc[mf][nf], 0, 0, 0);
          oacc[mf][nf] = __builtin_amdgcn_mfma_f32_16x16x32_bf16(sfl, vfh, oacc[mf][nf], 0, 0, 0);
          oacc[mf][nf] = __builtin_amdgcn_mfma_f32_16x16x32_bf16(sfh, vfl, oacc[mf][nf], 0, 0, 0);
        }
      }
    }
    __syncthreads();  // all waves done with sS (facc aliases it)
    for (int x = threadIdx.x; x < 32 * DHEAD; x += 512) ((float*)shraw)[x] = 0.f;
    __syncthreads();
    for (int w = 0; w < 8; ++w) {   // deterministic head+group sum
      if (wid == w) {
        #pragma unroll
        for (int mf = 0; mf < 2; ++mf)
          #pragma unroll
          for (int nf = 0; nf < NFO; ++nf)
            #pragma unroll
            for (int r = 0; r < 4; ++r) {
              int rr = mf * 16 + lg * 4 + r;
              facc[rr][nf * 16 + lr] += oacc[mf][nf][r] * hm3 / (float)(i0 + rr + 1);
            }
      }
      __syncthreads();
    }
    // fused residual + LN1 (H in-place; bf16-split out to HbfOut); wave owns 4 rows
    for (int rl = 0; rl < 4; ++rl) {
      int rr = wid * 4 + rl;
      size_t row = ((size_t)b * SEQ + i0 + rr) * EMB;
      int c0 = lane, c1 = lane + 64;
      float a0 = (DHEAD == 128) ? facc[rr][c0] : 0.f;
      float a1 = (DHEAD == 128) ? facc[rr][c1] : facc[rr][lane];
      float x0 = Hst[row + c0] + a0;
      float x1 = Hst[row + c1] + a1;
      float s1 = x0 + x1, s2 = x0 * x0 + x1 * x1;
      #pragma unroll
      for (int off = 1; off < 64; off <<= 1) {
        s1 += __shfl_xor(s1, off);
        s2 += __shfl_xor(s2, off);
      }
      float mu = s1 * (1.f / 128.f);
      float var = s2 * (1.f / 128.f) - mu * mu;
      float rs = rsqrt_acc(var + LN_EPS);
      float y0 = (x0 - mu) * rs * g[c0] + bta[c0];
      float y1 = (x1 - mu) * rs * g[c1] + bta[c1];
      Hst[row + c0] = y0; Hst[row + c1] = y1;
      unsigned short h0, l0, h1, l1; split2(y0, h0, l0); split2(y1, h1, l1);
      HbfOut[row + c0] = h0; HbfOut[hbPl + row + c0] = l0;
      HbfOut[row + c1] = h1; HbfOut[hbPl + row + c1] = l1;
    }
    __syncthreads();
  }
}

// ---------------- residual + LN2 ----------------
__global__ __launch_bounds__(256) void k_ln(const float* __restrict__ X,
                                            float* __restrict__ Hst,
                                            unsigned short* __restrict__ HbfOut, size_t hbPl,
                                            const float* __restrict__ g, const float* __restrict__ bta) {
  int wid = threadIdx.x >> 6, lane = threadIdx.x & 63;
  size_t row = ((size_t)blockIdx.x * 4 + wid) * EMB;
  int c0 = lane, c1 = lane + 64;
  float x0 = Hst[row + c0] + X[row + c0];
  float x1 = Hst[row + c1] + X[row + c1];
  float s1 = x0 + x1, s2 = x0 * x0 + x1 * x1;
  #pragma unroll
  for (int off = 1; off < 64; off <<= 1) {
    s1 += __shfl_xor(s1, off);
    s2 += __shfl_xor(s2, off);
  }
  float mu = s1 * (1.f / 128.f);
  float var = s2 * (1.f / 128.f) - mu * mu;
  float rs = rsqrt_acc(var + LN_EPS);
  float y0 = (x0 - mu) * rs * g[c0] + bta[c0];
  float y1 = (x1 - mu) * rs * g[c1] + bta[c1];
  Hst[row + c0] = y0; Hst[row + c1] = y1;
  unsigned short h0, l0, h1, l1; split2(y0, h0, l0); split2(y1, h1, l1);
  HbfOut[row + c0] = h0; HbfOut[hbPl + row + c0] = l0;
  HbfOut[row + c1] = h1; HbfOut[hbPl + row + c1] = l1;
}

// ---------------- readout ----------------
__global__ __launch_bounds__(64) void k_readout(const float* __restrict__ H,
                                                const float* __restrict__ W, const float* __restrict__ b0,
                                                float* __restrict__ out) {
  int idx = blockIdx.x;           // b*512 + p
  int b = idx >> 9, p = idx & 511;
  size_t row = ((size_t)b * SEQ + 2 * p) * EMB;
  int lane = threadIdx.x;
  float acc = H[row + lane] * W[lane] + H[row + 64 + lane] * W[64 + lane];
  #pragma unroll
  for (int off = 1; off < 64; off <<= 1) acc += __shfl_xor(acc, off);
  if (lane == 0) out[idx] = acc + b0[0];
}

extern "C" void kernel_launch(void* const* d_in, const int* in_sizes, int n_in,
                              void* d_out, int out_size, void* d_ws, size_t ws_size,
                              hipStream_t stream) {
  (void)in_sizes; (void)n_in; (void)out_size; (void)ws_size;
  const float* xs        = (const float*)d_in[0];
  const float* ys        = (const float*)d_in[1];
  const float* head_mask = (const float*)d_in[2];
  const float* read_in_W = (const float*)d_in[3];
  const float* read_in_b = (const float*)d_in[4];
  const float* qW        = (const float*)d_in[5];
  const float* vW        = (const float*)d_in[6];
  const float* qW_last   = (const float*)d_in[7];
  const float* kW_last   = (const float*)d_in[8];
  const float* vW_last   = (const float*)d_in[9];
  const float* ln1_g     = (const float*)d_in[10];
  const float* ln1_b     = (const float*)d_in[11];
  const float* ln2_g     = (const float*)d_in[12];
  const float* ln2_b     = (const float*)d_in[13];
  const float* mlp_W1    = (const float*)d_in[14];
  const float* mlp_b1    = (const float*)d_in[15];
  const float* mlp_W2    = (const float*)d_in[16];
  const float* mlp_b2    = (const float*)d_in[17];
  const float* ro_W      = (const float*)d_in[18];
  const float* ro_b      = (const float*)d_in[19];

  const size_t HPL   = (size_t)BS * SEQ * EMB;          // 2M
  const size_t QPL   = (size_t)BS * NHEAD * SEQ * 128;  // 8M
  const size_t VT64PL= (size_t)BS * NHEAD * 64 * SEQ;   // 4M
  const size_t MIDPL = (size_t)BS * SEQ * 512;          // 8M
  const size_t KMPL  = QPL;                              // 8M
  const size_t VTLPL = QPL;                              // 8M
  const size_t QVWPL = (size_t)11 * 512 * 128;
  const size_t W1PL  = (size_t)12 * 128 * 512;
  const size_t W2PL  = (size_t)12 * 512 * 128;
  const size_t LASTPL= (size_t)3 * 512 * 128;

  char* ws = (char*)d_ws;
  size_t off = 0;
  auto alloc = [&](size_t bytes) -> void* {
    void* p = ws + off;
    off += (bytes + 255) & ~(size_t)255;
    return p;
  };
  float* H             = (float*)alloc(HPL * 4);                  // 8 MB (in-place state)
  unsigned short* Hbf  = (unsigned short*)alloc(2 * HPL * 2);     // 8 MB
  unsigned short* Hbf2 = (unsigned short*)alloc(2 * HPL * 2);     // 8 MB
  unsigned short* qbuf = (unsigned short*)alloc(2 * QPL * 2);     // 32 MB
  float* resid = (float*)qbuf;   // alias: resid lives mlp2->ln2; qbuf lives proj->attn
  unsigned short* kmid = (unsigned short*)alloc(2 * KMPL * 2);    // 32 MB (vT(0-10) / mid / K-last)
  unsigned short* vTl  = (unsigned short*)alloc(2 * VTLPL * 2);   // 32 MB (last-layer vT)
  unsigned short* qvWT = (unsigned short*)alloc(2 * QVWPL * 2);
  unsigned short* W1T  = (unsigned short*)alloc(2 * W1PL * 2);
  unsigned short* W2T  = (unsigned short*)alloc(2 * W2PL * 2);
  unsigned short* lastT= (unsigned short*)alloc(2 * LASTPL * 2);

  { int tot = 11 * 512 * 128; k_prep_qv<<<dim3((tot + 255) / 256), 256, 0, stream>>>(qW, vW, qvWT, QVWPL); }
  { int tot = 12 * 512 * 128; k_transpose_pad<<<dim3((tot + 255) / 256), 256, 0, stream>>>(mlp_W1, W1T, W1PL, 12, 128, 512, 128, 512); }
  { int tot = 12 * 128 * 512; k_transpose_pad<<<dim3((tot + 255) / 256), 256, 0, stream>>>(mlp_W2, W2T, W2PL, 12, 512, 128, 512, 128); }
  { int tot = 512 * 128;
    k_transpose_pad<<<dim3((tot + 255) / 256), 256, 0, stream>>>(qW_last, lastT,          LASTPL, 1, 128, 512, 128, 512);
    k_transpose_pad<<<dim3((tot + 255) / 256), 256, 0, stream>>>(kW_last, lastT + 65536,  LASTPL, 1, 128, 512, 128, 512);
    k_transpose_pad<<<dim3((tot + 255) / 256), 256, 0, stream>>>(vW_last, lastT + 131072, LASTPL, 1, 128, 512, 128, 512); }

  k_combine_readin<<<dim3(BS * SEQ), 128, 0, stream>>>(xs, ys, read_in_W, read_in_b, H, Hbf, HPL);

  for (int l = 0; l < 11; ++l) {
    // fused q+v projection; v written directly transposed into kmid
    k_gemm<3, false><<<dim3(256, 8), 256, 0, stream>>>(
        Hbf, 128, HPL, qvWT + (size_t)l * 65536, QVWPL, nullptr, 512, 128,
        qbuf, QPL, kmid, VT64PL, nullptr, 0, nullptr);
    k_attn<64><<<dim3(256), 512, 0, stream>>>(
        qbuf, QPL, Hbf, HPL, (size_t)SEQ * EMB, 0, kmid, VT64PL, head_mask,
        H, Hbf2, HPL, ln1_g + l * 128, ln1_b + l * 128);
    k_gemm<0, true><<<dim3(256, 8), 256, 0, stream>>>(
        Hbf2, 128, HPL, W1T + (size_t)l * 65536, W1PL, mlp_b1 + l * 512, 512, 128,
        kmid, MIDPL, nullptr, 0, nullptr, 0, nullptr);
    k_gemm<1, false><<<dim3(256, 2), 256, 0, stream>>>(
        kmid, 512, MIDPL, W2T + (size_t)l * 65536, W2PL, mlp_b2 + l * 128, 128, 512,
        nullptr, 0, nullptr, 0, nullptr, 0, resid);
    k_ln<<<dim3(4096), 256, 0, stream>>>(resid, H, Hbf, HPL, ln2_g + l * 128, ln2_b + l * 128);
  }
  // last layer
  k_gemm<2, false><<<dim3(256, 24), 256, 0, stream>>>(
      Hbf, 128, HPL, lastT, LASTPL, nullptr, 1536, 128,
      qbuf, QPL, kmid, KMPL, vTl, VTLPL, nullptr);
  k_attn<128><<<dim3(256), 512, 0, stream>>>(
      qbuf, QPL, kmid, KMPL, (size_t)NHEAD * SEQ * 128, (size_t)SEQ * 128, vTl, VTLPL, head_mask,
      H, Hbf2, HPL, ln1_g + 11 * 128, ln1_b + 11 * 128);
  k_gemm<0, true><<<dim3(256, 8), 256, 0, stream>>>(
      Hbf2, 128, HPL, W1T + (size_t)11 * 65536, W1PL, mlp_b1 + 11 * 512, 512, 128,
      kmid, MIDPL, nullptr, 0, nullptr, 0, nullptr);
  k_gemm<1, false><<<dim3(256, 2), 256, 0, stream>>>(
      kmid, 512, MIDPL, W2T + (size_t)11 * 65536, W2PL, mlp_b2 + 11 * 128, 128, 512,
      nullptr, 0, nullptr, 0, nullptr, 0, resid);
  k_ln<<<dim3(4096), 256, 0, stream>>>(resid, H, Hbf, HPL, ln2_g + 11 * 128, ln2_b + 11 * 128);

  k_readout<<<dim3(8192), 64, 0, stream>>>(H, ro_W, ro_b, (float*)d_out);
}